// Round 2
// baseline (195.347 us; speedup 1.0000x reference)
//
#include <hip/hip_runtime.h>
#include <climits>

#define B   8192
#define D   256
#define NK  3
#define TOT 16384
#define NJC 16
#define JCH (B / NJC)   // 512
#define JC2 2048

// ---------------- workspace layout (bytes) ----------------
// cand_d : f32 [B*NJC*3]   @ 0         (1,572,864)
// cand_i : i32 [B*NJC*3]   @ 1572864   (1,572,864)
// invn   : f64 [TOT]       @ 3145728   (131,072)
// S_part : f64 [256*256]   @ 3276800   (524,288)
// S      : f64 [256]       @ 3801088   (2,048)
// comb   : f64 [TOT]       @ 3803136   (131,072)
// rank   : i32 [TOT]       @ 3934208   (65,536)
// total ~4.0 MB

// K1: per (i-block, j-chunk) partial top-3 nearest neighbors.
// EXACT f32 emulation of the reference: d2 = (sq_i + sq_j) - 2*dot with
// sq = (x*x + y*y) + z*z (rounded f32 ops), dot = sequential FMA chain
// (BLAS sgemm rank-1-update order), dist = sqrt_rn(max(d2,0)).
__global__ void knn_partial(const float* __restrict__ ref,
                            float* __restrict__ cand_d, int* __restrict__ cand_i) {
    __shared__ float px[JCH], py[JCH], pz[JCH], psq[JCH];
    int i  = blockIdx.x * 256 + threadIdx.x;
    int j0 = blockIdx.y * JCH;
    for (int t = threadIdx.x; t < JCH; t += 256) {
        float x = ref[(j0 + t) * 3 + 0];
        float y = ref[(j0 + t) * 3 + 1];
        float z = ref[(j0 + t) * 3 + 2];
        px[t] = x; py[t] = y; pz[t] = z;
        psq[t] = __fadd_rn(__fadd_rn(__fmul_rn(x, x), __fmul_rn(y, y)), __fmul_rn(z, z));
    }
    __syncthreads();
    float qx = ref[i * 3 + 0], qy = ref[i * 3 + 1], qz = ref[i * 3 + 2];
    float qsq = __fadd_rn(__fadd_rn(__fmul_rn(qx, qx), __fmul_rn(qy, qy)), __fmul_rn(qz, qz));
    float b0 = INFINITY, b1 = INFINITY, b2 = INFINITY;
    int   i0 = INT_MAX, i1 = INT_MAX, i2 = INT_MAX;
    for (int t = 0; t < JCH; ++t) {
        int j = j0 + t;
        if (j == i) continue;
        float dot = __fmaf_rn(qz, pz[t], __fmaf_rn(qy, py[t], __fmul_rn(qx, px[t])));
        float d2  = __fsub_rn(__fadd_rn(qsq, psq[t]), __fmul_rn(2.0f, dot));
        float d   = __fsqrt_rn(fmaxf(d2, 0.0f));
        if (d < b2) {                      // strict < + ascending j => stable ties
            if (d < b1) {
                b2 = b1; i2 = i1;
                if (d < b0) { b1 = b0; i1 = i0; b0 = d; i0 = j; }
                else        { b1 = d; i1 = j; }
            } else { b2 = d; i2 = j; }
        }
    }
    int base = (i * NJC + blockIdx.y) * 3;
    cand_d[base + 0] = b0; cand_d[base + 1] = b1; cand_d[base + 2] = b2;
    cand_i[base + 0] = i0; cand_i[base + 1] = i1; cand_i[base + 2] = i2;
}

// K2: merge NJC partial top-3 lists -> final top-3, lexicographic (d, idx) tie-break
__global__ void knn_merge(const float* __restrict__ cand_d, const int* __restrict__ cand_i,
                          float* __restrict__ out_closest) {
    int i = blockIdx.x * 256 + threadIdx.x;
    float b0 = INFINITY, b1 = INFINITY, b2 = INFINITY;
    int   i0 = INT_MAX, i1 = INT_MAX, i2 = INT_MAX;
    int base = i * NJC * 3;
    for (int c = 0; c < NJC * 3; ++c) {
        float d  = cand_d[base + c];
        int   ix = cand_i[base + c];
        bool lt2 = (d < b2) || (d == b2 && ix < i2);
        if (lt2) {
            bool lt1 = (d < b1) || (d == b1 && ix < i1);
            if (lt1) {
                b2 = b1; i2 = i1;
                bool lt0 = (d < b0) || (d == b0 && ix < i0);
                if (lt0) { b1 = b0; i1 = i0; b0 = d; i0 = ix; }
                else     { b1 = d; i1 = ix; }
            } else { b2 = d; i2 = ix; }
        }
    }
    out_closest[i * 3 + 0] = (float)i0;
    out_closest[i * 3 + 1] = (float)i1;
    out_closest[i * 3 + 2] = (float)i2;
}

// K3: per-row L2 norm -> 1/max(norm, eps), f64. One wave per row.
__global__ void row_norms(const float* __restrict__ mem_tokens, const float* __restrict__ new_tokens,
                          double* __restrict__ invn) {
    int wave = threadIdx.x >> 6;
    int lane = threadIdx.x & 63;
    int r = blockIdx.x * 4 + wave;
    const float* row = (r < B) ? (mem_tokens + (size_t)r * D) : (new_tokens + (size_t)(r - B) * D);
    float4 v = *(const float4*)(row + lane * 4);
    double s = (double)v.x * (double)v.x + (double)v.y * (double)v.y +
               (double)v.z * (double)v.z + (double)v.w * (double)v.w;
    for (int off = 32; off; off >>= 1) s += __shfl_down(s, off, 64);
    if (lane == 0) {
        double n = sqrt(s);
        if (n < 1e-12) n = 1e-12;
        invn[r] = 1.0 / n;
    }
}

// K4: partial S = sum over rows of normalized tokens (256 blocks x 64 rows)
__global__ void s_partial(const float* __restrict__ mem_tokens, const float* __restrict__ new_tokens,
                          const double* __restrict__ invn, double* __restrict__ S_part) {
    int d  = threadIdx.x;
    int r0 = blockIdx.x * 64;
    double acc = 0.0;
    for (int k = 0; k < 64; ++k) {
        int r = r0 + k;
        const float* row = (r < B) ? (mem_tokens + (size_t)r * D) : (new_tokens + (size_t)(r - B) * D);
        acc += (double)row[d] * invn[r];
    }
    S_part[blockIdx.x * 256 + d] = acc;
}

// K5: reduce 256 partials -> S[256]
__global__ void s_reduce(const double* __restrict__ S_part, double* __restrict__ S) {
    int d = threadIdx.x;
    double s = 0.0;
    for (int b = 0; b < 256; ++b) s += S_part[b * 256 + d];
    S[d] = s;
}

// K6: combined[i] = age_i - invn_i * (t_i . S); also zero rank[]. One wave per row.
__global__ void combined_kernel(const float* __restrict__ mem_tokens, const float* __restrict__ new_tokens,
                                const float* __restrict__ mem_ages,
                                const double* __restrict__ invn, const double* __restrict__ S,
                                double* __restrict__ comb, int* __restrict__ rank) {
    int wave = threadIdx.x >> 6;
    int lane = threadIdx.x & 63;
    int r = blockIdx.x * 4 + wave;
    const float* row = (r < B) ? (mem_tokens + (size_t)r * D) : (new_tokens + (size_t)(r - B) * D);
    float4 v = *(const float4*)(row + lane * 4);
    const double* Sp = S + lane * 4;
    double s = (double)v.x * Sp[0] + (double)v.y * Sp[1] +
               (double)v.z * Sp[2] + (double)v.w * Sp[3];
    for (int off = 32; off; off >>= 1) s += __shfl_down(s, off, 64);
    if (lane == 0) {
        double age = (r < B) ? (double)mem_ages[r] + 1.0 : 0.0;
        comb[r] = age - s * invn[r];
        rank[r] = 0;
    }
}

// K7: stable rank count. grid (64, 8): 256 i's per block, 2048 j's per chunk.
__global__ void rank_count(const double* __restrict__ comb, int* __restrict__ rank) {
    __shared__ double cl[JC2];
    int i  = blockIdx.x * 256 + threadIdx.x;
    int j0 = blockIdx.y * JC2;
    for (int t = threadIdx.x; t < JC2; t += 256) cl[t] = comb[j0 + t];
    __syncthreads();
    double ci = comb[i];
    int cnt = 0;
    for (int t = 0; t < JC2; ++t) {
        double cj = cl[t];
        int j = j0 + t;
        cnt += (cj < ci) || (cj == ci && j < i);
    }
    atomicAdd(&rank[i], cnt);
}

// K8: scatter kept rows to out[rank[i]]. One block per source row.
__global__ void gather(const float* __restrict__ mem_keys, const float* __restrict__ mem_tokens,
                       const float* __restrict__ new_tokens, const float* __restrict__ mem_ages,
                       const int* __restrict__ rank,
                       float* __restrict__ out_keys, float* __restrict__ out_tokens,
                       float* __restrict__ out_ages) {
    int r  = blockIdx.x;
    int rk = rank[r];
    if (rk >= B) return;
    int tid = threadIdx.x;
    if (r < B) {
        out_tokens[(size_t)rk * D + tid] = mem_tokens[(size_t)r * D + tid];
        const float* kb = mem_keys + (size_t)r * 3 * D;
        float* ob = out_keys + (size_t)rk * 3 * D;
        ob[tid]         = kb[tid];
        ob[D + tid]     = kb[D + tid];
        ob[2 * D + tid] = kb[2 * D + tid];
        if (tid == 0) out_ages[rk] = mem_ages[r] + 1.0f;
    } else {
        int bb = r - B;
        float v = new_tokens[(size_t)bb * D + tid];
        out_tokens[(size_t)rk * D + tid] = v;
        float* ob = out_keys + (size_t)rk * 3 * D;
        ob[tid] = v; ob[D + tid] = v; ob[2 * D + tid] = v;
        if (tid == 0) out_ages[rk] = 0.0f;
    }
}

extern "C" void kernel_launch(void* const* d_in, const int* in_sizes, int n_in,
                              void* d_out, int out_size, void* d_ws, size_t ws_size,
                              hipStream_t stream) {
    const float* new_tokens = (const float*)d_in[0];  // [8192,256]
    const float* ref_pts    = (const float*)d_in[1];  // [8192,3]
    const float* mem_keys   = (const float*)d_in[2];  // [8192,3,256]
    const float* mem_tokens = (const float*)d_in[3];  // [8192,256]
    const float* mem_ages   = (const float*)d_in[4];  // [8192]

    char* ws = (char*)d_ws;
    float*  cand_d = (float*) (ws + 0);
    int*    cand_i = (int*)   (ws + 1572864);
    double* invn   = (double*)(ws + 3145728);
    double* S_part = (double*)(ws + 3276800);
    double* S      = (double*)(ws + 3801088);
    double* comb   = (double*)(ws + 3803136);
    int*    rank   = (int*)   (ws + 3934208);

    float* out = (float*)d_out;
    float* out_keys    = out;                       // 8192*3*256 = 6291456
    float* out_tokens  = out + 6291456;             // 8192*256   = 2097152
    float* out_ages    = out + 6291456 + 2097152;   // 8192
    float* out_closest = out_ages + 8192;           // 8192*3 (written as float)

    knn_partial<<<dim3(B / 256, NJC), 256, 0, stream>>>(ref_pts, cand_d, cand_i);
    knn_merge<<<B / 256, 256, 0, stream>>>(cand_d, cand_i, out_closest);
    row_norms<<<TOT / 4, 256, 0, stream>>>(mem_tokens, new_tokens, invn);
    s_partial<<<256, 256, 0, stream>>>(mem_tokens, new_tokens, invn, S_part);
    s_reduce<<<1, 256, 0, stream>>>(S_part, S);
    combined_kernel<<<TOT / 4, 256, 0, stream>>>(mem_tokens, new_tokens, mem_ages, invn, S, comb, rank);
    rank_count<<<dim3(TOT / 256, TOT / JC2), 256, 0, stream>>>(comb, rank);
    gather<<<TOT, 256, 0, stream>>>(mem_keys, mem_tokens, new_tokens, mem_ages, rank,
                                    out_keys, out_tokens, out_ages);
}

// Round 3
// 154.567 us; speedup vs baseline: 1.2638x; 1.2638x over previous
//
#include <hip/hip_runtime.h>
#include <climits>

#define B   8192
#define D   256
#define NK  3
#define TOT 16384
#define NJC 32
#define JCH (B / NJC)   // 256
#define JC2 256

// ---------------- workspace layout (bytes) ----------------
// cand_d : f32 [B*NJC*3]   @ 0         (3,145,728)
// cand_i : i32 [B*NJC*3]   @ 3145728   (3,145,728)
// invn   : f64 [TOT]       @ 6291456   (131,072)
// S_part : f64 [256*256]   @ 6422528   (524,288)
// S      : f64 [256]       @ 6946816   (2,048)
// comb   : f64 [TOT]       @ 6948864   (131,072)
// rank   : i32 [TOT]       @ 7079936   (65,536)
// total ~7.15 MB

// K1: per (i-block, j-chunk) partial top-3 nearest neighbors.
// EXACT f32 emulation of the reference: d2 = (sq_i + sq_j) - 2*dot with
// sq = (x*x + y*y) + z*z (rounded f32 ops), dot = sequential FMA chain,
// dist = sqrt_rn(max(d2,0)).
__global__ void knn_partial(const float* __restrict__ ref,
                            float* __restrict__ cand_d, int* __restrict__ cand_i) {
    __shared__ float4 pts[JCH];
    int i  = blockIdx.x * 256 + threadIdx.x;
    int j0 = blockIdx.y * JCH;
    {
        int t = threadIdx.x;                     // JCH == blockDim.x == 256
        float x = ref[(j0 + t) * 3 + 0];
        float y = ref[(j0 + t) * 3 + 1];
        float z = ref[(j0 + t) * 3 + 2];
        float sq = __fadd_rn(__fadd_rn(__fmul_rn(x, x), __fmul_rn(y, y)), __fmul_rn(z, z));
        pts[t] = make_float4(x, y, z, sq);
    }
    __syncthreads();
    float qx = ref[i * 3 + 0], qy = ref[i * 3 + 1], qz = ref[i * 3 + 2];
    float qsq = __fadd_rn(__fadd_rn(__fmul_rn(qx, qx), __fmul_rn(qy, qy)), __fmul_rn(qz, qz));
    float b0 = INFINITY, b1 = INFINITY, b2 = INFINITY;
    int   i0 = INT_MAX, i1 = INT_MAX, i2 = INT_MAX;
    #pragma unroll 4
    for (int t = 0; t < JCH; ++t) {
        float4 p  = pts[t];
        float dot = __fmaf_rn(qz, p.z, __fmaf_rn(qy, p.y, __fmul_rn(qx, p.x)));
        float d2  = __fsub_rn(__fadd_rn(qsq, p.w), __fmul_rn(2.0f, dot));
        float d   = __fsqrt_rn(fmaxf(d2, 0.0f));
        int j = j0 + t;
        if (j == i) d = INFINITY;                // diagonal excluded, branchless
        if (d < b2) {                            // strict < + ascending j => stable ties
            if (d < b1) {
                b2 = b1; i2 = i1;
                if (d < b0) { b1 = b0; i1 = i0; b0 = d; i0 = j; }
                else        { b1 = d; i1 = j; }
            } else { b2 = d; i2 = j; }
        }
    }
    int base = (i * NJC + blockIdx.y) * 3;
    cand_d[base + 0] = b0; cand_d[base + 1] = b1; cand_d[base + 2] = b2;
    cand_i[base + 0] = i0; cand_i[base + 1] = i1; cand_i[base + 2] = i2;
}

// K2: merge NJC partial top-3 lists -> final top-3, lexicographic (d, idx) tie-break
__global__ void knn_merge(const float* __restrict__ cand_d, const int* __restrict__ cand_i,
                          float* __restrict__ out_closest) {
    int i = blockIdx.x * 256 + threadIdx.x;
    float b0 = INFINITY, b1 = INFINITY, b2 = INFINITY;
    int   i0 = INT_MAX, i1 = INT_MAX, i2 = INT_MAX;
    int base = i * NJC * 3;
    for (int c = 0; c < NJC * 3; ++c) {
        float d  = cand_d[base + c];
        int   ix = cand_i[base + c];
        bool lt2 = (d < b2) || (d == b2 && ix < i2);
        if (lt2) {
            bool lt1 = (d < b1) || (d == b1 && ix < i1);
            if (lt1) {
                b2 = b1; i2 = i1;
                bool lt0 = (d < b0) || (d == b0 && ix < i0);
                if (lt0) { b1 = b0; i1 = i0; b0 = d; i0 = ix; }
                else     { b1 = d; i1 = ix; }
            } else { b2 = d; i2 = ix; }
        }
    }
    out_closest[i * 3 + 0] = (float)i0;
    out_closest[i * 3 + 1] = (float)i1;
    out_closest[i * 3 + 2] = (float)i2;
}

// K3: per-row L2 norm -> 1/max(norm, eps), f64. One wave per row.
__global__ void row_norms(const float* __restrict__ mem_tokens, const float* __restrict__ new_tokens,
                          double* __restrict__ invn) {
    int wave = threadIdx.x >> 6;
    int lane = threadIdx.x & 63;
    int r = blockIdx.x * 4 + wave;
    const float* row = (r < B) ? (mem_tokens + (size_t)r * D) : (new_tokens + (size_t)(r - B) * D);
    float4 v = *(const float4*)(row + lane * 4);
    double s = (double)v.x * (double)v.x + (double)v.y * (double)v.y +
               (double)v.z * (double)v.z + (double)v.w * (double)v.w;
    for (int off = 32; off; off >>= 1) s += __shfl_down(s, off, 64);
    if (lane == 0) {
        double n = sqrt(s);
        if (n < 1e-12) n = 1e-12;
        invn[r] = 1.0 / n;
    }
}

// K4: partial S = sum over rows of normalized tokens (256 blocks x 64 rows)
__global__ void s_partial(const float* __restrict__ mem_tokens, const float* __restrict__ new_tokens,
                          const double* __restrict__ invn, double* __restrict__ S_part) {
    int d  = threadIdx.x;
    int r0 = blockIdx.x * 64;
    double acc = 0.0;
    for (int k = 0; k < 64; ++k) {
        int r = r0 + k;
        const float* row = (r < B) ? (mem_tokens + (size_t)r * D) : (new_tokens + (size_t)(r - B) * D);
        acc += (double)row[d] * invn[r];
    }
    S_part[blockIdx.x * 256 + d] = acc;
}

// K5: reduce 256 partials -> S[256]
__global__ void s_reduce(const double* __restrict__ S_part, double* __restrict__ S) {
    int d = threadIdx.x;
    double s = 0.0;
    for (int b = 0; b < 256; ++b) s += S_part[b * 256 + d];
    S[d] = s;
}

// K6: combined[i] = age_i - invn_i * (t_i . S); also zero rank[]. One wave per row.
__global__ void combined_kernel(const float* __restrict__ mem_tokens, const float* __restrict__ new_tokens,
                                const float* __restrict__ mem_ages,
                                const double* __restrict__ invn, const double* __restrict__ S,
                                double* __restrict__ comb, int* __restrict__ rank) {
    int wave = threadIdx.x >> 6;
    int lane = threadIdx.x & 63;
    int r = blockIdx.x * 4 + wave;
    const float* row = (r < B) ? (mem_tokens + (size_t)r * D) : (new_tokens + (size_t)(r - B) * D);
    float4 v = *(const float4*)(row + lane * 4);
    const double* Sp = S + lane * 4;
    double s = (double)v.x * Sp[0] + (double)v.y * Sp[1] +
               (double)v.z * Sp[2] + (double)v.w * Sp[3];
    for (int off = 32; off; off >>= 1) s += __shfl_down(s, off, 64);
    if (lane == 0) {
        double age = (r < B) ? (double)mem_ages[r] + 1.0 : 0.0;
        comb[r] = age - s * invn[r];
        rank[r] = 0;
    }
}

// K7: stable rank count, 4 consecutive i per thread, split-loop formulation.
// rank[i] = #{j : cj<ci} + #{j<i : cj==ci}  (exact lexicographic order)
// For j < all i's:  count (cj <= ci).  For j > all i's: count (cj < ci).
// Straddle window (<=4 iters): full lexicographic compare.
__global__ void rank_count(const double* __restrict__ comb, int* __restrict__ rank) {
    __shared__ double cl[JC2];
    int base = (blockIdx.x * 256 + threadIdx.x) * 4;
    int j0   = blockIdx.y * JC2;
    for (int t = threadIdx.x; t < JC2; t += 256) cl[t] = comb[j0 + t];
    __syncthreads();
    double c0 = comb[base + 0], c1 = comb[base + 1];
    double c2 = comb[base + 2], c3 = comb[base + 3];
    int n0 = 0, n1 = 0, n2 = 0, n3 = 0;
    int lo = base - j0;       if (lo < 0) lo = 0; if (lo > JC2) lo = JC2;
    int hi = base + 4 - j0;   if (hi < 0) hi = 0; if (hi > JC2) hi = JC2;
    for (int t = 0; t < lo; ++t) {           // j < base <= all i
        double cj = cl[t];
        n0 += (cj <= c0); n1 += (cj <= c1); n2 += (cj <= c2); n3 += (cj <= c3);
    }
    for (int t = lo; t < hi; ++t) {          // straddle: exact tie-break
        double cj = cl[t];
        int j = j0 + t;
        n0 += (cj < c0) || (cj == c0 && j < base + 0);
        n1 += (cj < c1) || (cj == c1 && j < base + 1);
        n2 += (cj < c2) || (cj == c2 && j < base + 2);
        n3 += (cj < c3) || (cj == c3 && j < base + 3);
    }
    for (int t = hi; t < JC2; ++t) {         // j >= base+4 > all i
        double cj = cl[t];
        n0 += (cj < c0); n1 += (cj < c1); n2 += (cj < c2); n3 += (cj < c3);
    }
    atomicAdd(&rank[base + 0], n0);
    atomicAdd(&rank[base + 1], n1);
    atomicAdd(&rank[base + 2], n2);
    atomicAdd(&rank[base + 3], n3);
}

// K8: scatter kept rows to out[rank[i]], float4-vectorized. One block per source row.
// 256 threads = 64 token-float4s (t<64) + 192 key-float4s (t>=64).
__global__ void gather(const float* __restrict__ mem_keys, const float* __restrict__ mem_tokens,
                       const float* __restrict__ new_tokens, const float* __restrict__ mem_ages,
                       const int* __restrict__ rank,
                       float* __restrict__ out_keys, float* __restrict__ out_tokens,
                       float* __restrict__ out_ages) {
    int r  = blockIdx.x;
    int rk = rank[r];
    if (rk >= B) return;
    int t = threadIdx.x;
    float4* ot = (float4*)(out_tokens + (size_t)rk * D);
    float4* ok = (float4*)(out_keys + (size_t)rk * 3 * D);
    if (r < B) {
        if (t < 64) {
            const float4* st = (const float4*)(mem_tokens + (size_t)r * D);
            ot[t] = st[t];
        } else {
            const float4* sk = (const float4*)(mem_keys + (size_t)r * 3 * D);
            ok[t - 64] = sk[t - 64];
        }
        if (t == 0) out_ages[rk] = mem_ages[r] + 1.0f;
    } else {
        const float4* nt = (const float4*)(new_tokens + (size_t)(r - B) * D);
        float4 v = nt[t & 63];
        if (t < 64) ot[t] = v;
        else        ok[t - 64] = v;
        if (t == 0) out_ages[rk] = 0.0f;
    }
}

extern "C" void kernel_launch(void* const* d_in, const int* in_sizes, int n_in,
                              void* d_out, int out_size, void* d_ws, size_t ws_size,
                              hipStream_t stream) {
    const float* new_tokens = (const float*)d_in[0];  // [8192,256]
    const float* ref_pts    = (const float*)d_in[1];  // [8192,3]
    const float* mem_keys   = (const float*)d_in[2];  // [8192,3,256]
    const float* mem_tokens = (const float*)d_in[3];  // [8192,256]
    const float* mem_ages   = (const float*)d_in[4];  // [8192]

    char* ws = (char*)d_ws;
    float*  cand_d = (float*) (ws + 0);
    int*    cand_i = (int*)   (ws + 3145728);
    double* invn   = (double*)(ws + 6291456);
    double* S_part = (double*)(ws + 6422528);
    double* S      = (double*)(ws + 6946816);
    double* comb   = (double*)(ws + 6948864);
    int*    rank   = (int*)   (ws + 7079936);

    float* out = (float*)d_out;
    float* out_keys    = out;                       // 8192*3*256 = 6291456
    float* out_tokens  = out + 6291456;             // 8192*256   = 2097152
    float* out_ages    = out + 6291456 + 2097152;   // 8192
    float* out_closest = out_ages + 8192;           // 8192*3 (written as float)

    knn_partial<<<dim3(B / 256, NJC), 256, 0, stream>>>(ref_pts, cand_d, cand_i);
    knn_merge<<<B / 256, 256, 0, stream>>>(cand_d, cand_i, out_closest);
    row_norms<<<TOT / 4, 256, 0, stream>>>(mem_tokens, new_tokens, invn);
    s_partial<<<256, 256, 0, stream>>>(mem_tokens, new_tokens, invn, S_part);
    s_reduce<<<1, 256, 0, stream>>>(S_part, S);
    combined_kernel<<<TOT / 4, 256, 0, stream>>>(mem_tokens, new_tokens, mem_ages, invn, S, comb, rank);
    rank_count<<<dim3(TOT / (256 * 4), TOT / JC2), 256, 0, stream>>>(comb, rank);
    gather<<<TOT, 256, 0, stream>>>(mem_keys, mem_tokens, new_tokens, mem_ages, rank,
                                    out_keys, out_tokens, out_ages);
}